// Round 6
// baseline (205.644 us; speedup 1.0000x reference)
//
#include <hip/hip_runtime.h>
#include <math.h>

constexpr int Bb = 4, Cc = 64, Hh = 256, Ww = 256;

#define LOG2E 1.44269504088896340736f
#define LN2   0.69314718055994530942f

__device__ __forceinline__ unsigned int fenc(float f) {
  unsigned int u = __float_as_uint(f);
  return (u & 0x80000000u) ? ~u : (u | 0x80000000u);
}
__device__ __forceinline__ float fdec(unsigned int k) {
  return __uint_as_float((k & 0x80000000u) ? (k ^ 0x80000000u) : ~k);
}

// entropy = ln(s) - ws/s, s = 3x3 box of e^v, ws = 3x3 box of v*e^v
// (shift-invariant softmax entropy; N(0,1) inputs so e^v safe in fp32).
// Zero-padding contributes a=1, b=0 == exp of a loaded 0.
//
// Grid: B*H = 1024 blocks (one output row each; 4 blocks/CU -> 100% occ).
// Block (64,8): ty = 8 channels each, thread = 4 cols (float4).
// Channel loop software-double-buffered: next channel's 3 row loads are
// issued before the current channel's exp chain.
__global__ __launch_bounds__(512, 8) void entropy_kernel(const float* __restrict__ x,
                                                         float* __restrict__ e,
                                                         unsigned int* __restrict__ stats) {
  const int b = blockIdx.x >> 8;          // / Hh
  const int h = blockIdx.x & (Hh - 1);
  const int tx = threadIdx.x;             // 0..63
  const int ty = threadIdx.y;             // 0..7
  const int w0 = tx * 4;

  const size_t planeStride = (size_t)Hh * Ww;
  const float* xb = x + ((size_t)b * Cc + (size_t)ty * 8) * planeStride + w0;
  const bool up_ok = (h > 0), dn_ok = (h < Hh - 1);
  const size_t rowUp = (size_t)(h - 1) * Ww;
  const size_t rowMd = (size_t)h * Ww;
  const size_t rowDn = (size_t)(h + 1) * Ww;

  float acc[4] = {0.f, 0.f, 0.f, 0.f};

  float4 vbuf[3];
  vbuf[0] = up_ok ? *reinterpret_cast<const float4*>(xb + rowUp) : make_float4(0.f, 0.f, 0.f, 0.f);
  vbuf[1] = *reinterpret_cast<const float4*>(xb + rowMd);
  vbuf[2] = dn_ok ? *reinterpret_cast<const float4*>(xb + rowDn) : make_float4(0.f, 0.f, 0.f, 0.f);

  for (int cc = 0; cc < 8; ++cc) {
    float4 vnext[3];
    if (cc < 7) {
      const float* p = xb + (size_t)(cc + 1) * planeStride;
      vnext[0] = up_ok ? *reinterpret_cast<const float4*>(p + rowUp) : make_float4(0.f, 0.f, 0.f, 0.f);
      vnext[1] = *reinterpret_cast<const float4*>(p + rowMd);
      vnext[2] = dn_ok ? *reinterpret_cast<const float4*>(p + rowDn) : make_float4(0.f, 0.f, 0.f, 0.f);
    }

    float s[4] = {0.f, 0.f, 0.f, 0.f};
    float w[4] = {0.f, 0.f, 0.f, 0.f};
#pragma unroll
    for (int j = 0; j < 3; ++j) {
      const float* vp = &vbuf[j].x;
      float a[4], bb4[4];
#pragma unroll
      for (int i = 0; i < 4; ++i) {
        float t = __builtin_amdgcn_exp2f(vp[i] * LOG2E);  // e^v
        a[i] = t;
        bb4[i] = vp[i] * t;                               // v * e^v
      }
      float la = __shfl_up(a[3], 1, 64);
      float lb = __shfl_up(bb4[3], 1, 64);
      float ra = __shfl_down(a[0], 1, 64);
      float rb = __shfl_down(bb4[0], 1, 64);
      la = (tx == 0) ? 1.f : la;   lb = (tx == 0) ? 0.f : lb;
      ra = (tx == 63) ? 1.f : ra;  rb = (tx == 63) ? 0.f : rb;
      s[0] += la + a[0] + a[1];
      s[1] += a[0] + a[1] + a[2];
      s[2] += a[1] + a[2] + a[3];
      s[3] += a[2] + a[3] + ra;
      w[0] += lb + bb4[0] + bb4[1];
      w[1] += bb4[0] + bb4[1] + bb4[2];
      w[2] += bb4[1] + bb4[2] + bb4[3];
      w[3] += bb4[2] + bb4[3] + rb;
    }
#pragma unroll
    for (int i = 0; i < 4; ++i)
      acc[i] += LN2 * __builtin_amdgcn_logf(s[i]) - w[i] * __builtin_amdgcn_rcpf(s[i]);

    if (cc < 7) {
      vbuf[0] = vnext[0];
      vbuf[1] = vnext[1];
      vbuf[2] = vnext[2];
    }
  }

  // Reduce the 8 channel groups (8 KiB LDS).
  __shared__ float red[8][4][64];
#pragma unroll
  for (int i = 0; i < 4; ++i) red[ty][i][tx] = acc[i];
  __syncthreads();
  if (ty == 0) {
    float4 o;
    float* op = &o.x;
    float mn = INFINITY, mx = -INFINITY;
#pragma unroll
    for (int i = 0; i < 4; ++i) {
      float v = 0.f;
#pragma unroll
      for (int g = 0; g < 8; ++g) v += red[g][i][tx];
      v *= (1.0f / Cc);
      op[i] = v;
      mn = fminf(mn, v);
      mx = fmaxf(mx, v);
    }
    *reinterpret_cast<float4*>(e + (size_t)(b * Hh + h) * Ww + w0) = o;

#pragma unroll
    for (int off = 32; off > 0; off >>= 1) {
      mn = fminf(mn, __shfl_down(mn, off, 64));
      mx = fmaxf(mx, __shfl_down(mx, off, 64));
    }
    if (tx == 0) {
      atomicMin(&stats[b], fenc(mn));
      atomicMax(&stats[4 + b], fenc(mx));
    }
  }
}

// In-place normalize d_out. 65536 threads, 4 elements each (float4).
__global__ __launch_bounds__(256) void norm_kernel(float* __restrict__ e,
                                                   const unsigned int* __restrict__ stats) {
  const int t = blockIdx.x * 256 + threadIdx.x;           // 0..65535
  const int b = t >> 14;                                  // (t*4) >> 16
  const float mn = fdec(stats[b]);
  const float mx = fdec(stats[4 + b]);
  const float inv = 1.0f / fmaxf(mx - mn, 1e-6f);
  float4 v = reinterpret_cast<float4*>(e)[t];
  v.x = (v.x - mn) * inv;
  v.y = (v.y - mn) * inv;
  v.z = (v.z - mn) * inv;
  v.w = (v.w - mn) * inv;
  reinterpret_cast<float4*>(e)[t] = v;
}

extern "C" void kernel_launch(void* const* d_in, const int* in_sizes, int n_in,
                              void* d_out, int out_size, void* d_ws, size_t ws_size,
                              hipStream_t stream) {
  const float* x = (const float*)d_in[0];
  float* out = (float*)d_out;                 // e, then normalized in place
  unsigned int* stats = (unsigned int*)d_ws;  // 8 uints

  // Init: min keys -> 0xFFFFFFFF, max keys -> 0.
  hipMemsetAsync(stats, 0xFF, 4 * sizeof(unsigned int), stream);
  hipMemsetAsync(stats + 4, 0x00, 4 * sizeof(unsigned int), stream);

  entropy_kernel<<<dim3(Bb * Hh), dim3(64, 8), 0, stream>>>(x, out, stats);
  norm_kernel<<<dim3((Bb * Hh * Ww / 4) / 256), dim3(256), 0, stream>>>(out, stats);
}

// Round 7
// 108.822 us; speedup vs baseline: 1.8897x; 1.8897x over previous
//
#include <hip/hip_runtime.h>
#include <math.h>

constexpr int Bb = 4, Cc = 64, Hh = 256, Ww = 256;

#define LOG2E 1.44269504088896340736f
#define LN2   0.69314718055994530942f

__device__ __forceinline__ unsigned int fenc(float f) {
  unsigned int u = __float_as_uint(f);
  return (u & 0x80000000u) ? ~u : (u | 0x80000000u);
}
__device__ __forceinline__ float fdec(unsigned int k) {
  return __uint_as_float((k & 0x80000000u) ? (k ^ 0x80000000u) : ~k);
}

// entropy = ln(s) - ws/s, s = 3x3 box of e^v, ws = 3x3 box of v*e^v
// (shift-invariant softmax entropy; N(0,1) inputs so e^v safe in fp32).
// Zero-padding contributes a=1, b=0 == exp of a loaded 0.
//
// Grid: B*H = 1024 blocks (one output row each; 4 blocks/CU).
// Block (64,8): ty = 8 channels each, thread = 4 cols (float4).
// Channel loop software-double-buffered.
// NOTE: launch_bounds min-waves must stay at 4 — forcing 8 caps VGPR at 32
// and spills catastrophically (round 6: 300MB scratch fetch, 4x slowdown).
__global__ __launch_bounds__(512, 4) void entropy_kernel(const float* __restrict__ x,
                                                         float* __restrict__ e,
                                                         unsigned int* __restrict__ stats) {
  const int b = blockIdx.x >> 8;          // / Hh
  const int h = blockIdx.x & (Hh - 1);
  const int tx = threadIdx.x;             // 0..63
  const int ty = threadIdx.y;             // 0..7
  const int w0 = tx * 4;

  const size_t planeStride = (size_t)Hh * Ww;
  const float* xb = x + ((size_t)b * Cc + (size_t)ty * 8) * planeStride + w0;
  const bool up_ok = (h > 0), dn_ok = (h < Hh - 1);
  const size_t rowUp = (size_t)(h - 1) * Ww;
  const size_t rowMd = (size_t)h * Ww;
  const size_t rowDn = (size_t)(h + 1) * Ww;

  float acc[4] = {0.f, 0.f, 0.f, 0.f};

  float4 vbuf[3];
  vbuf[0] = up_ok ? *reinterpret_cast<const float4*>(xb + rowUp) : make_float4(0.f, 0.f, 0.f, 0.f);
  vbuf[1] = *reinterpret_cast<const float4*>(xb + rowMd);
  vbuf[2] = dn_ok ? *reinterpret_cast<const float4*>(xb + rowDn) : make_float4(0.f, 0.f, 0.f, 0.f);

  for (int cc = 0; cc < 8; ++cc) {
    float4 vnext[3];
    if (cc < 7) {
      const float* p = xb + (size_t)(cc + 1) * planeStride;
      vnext[0] = up_ok ? *reinterpret_cast<const float4*>(p + rowUp) : make_float4(0.f, 0.f, 0.f, 0.f);
      vnext[1] = *reinterpret_cast<const float4*>(p + rowMd);
      vnext[2] = dn_ok ? *reinterpret_cast<const float4*>(p + rowDn) : make_float4(0.f, 0.f, 0.f, 0.f);
    }

    float s[4] = {0.f, 0.f, 0.f, 0.f};
    float w[4] = {0.f, 0.f, 0.f, 0.f};
#pragma unroll
    for (int j = 0; j < 3; ++j) {
      const float* vp = &vbuf[j].x;
      float a[4], bb4[4];
#pragma unroll
      for (int i = 0; i < 4; ++i) {
        float t = __builtin_amdgcn_exp2f(vp[i] * LOG2E);  // e^v
        a[i] = t;
        bb4[i] = vp[i] * t;                               // v * e^v
      }
      float la = __shfl_up(a[3], 1, 64);
      float lb = __shfl_up(bb4[3], 1, 64);
      float ra = __shfl_down(a[0], 1, 64);
      float rb = __shfl_down(bb4[0], 1, 64);
      la = (tx == 0) ? 1.f : la;   lb = (tx == 0) ? 0.f : lb;
      ra = (tx == 63) ? 1.f : ra;  rb = (tx == 63) ? 0.f : rb;
      s[0] += la + a[0] + a[1];
      s[1] += a[0] + a[1] + a[2];
      s[2] += a[1] + a[2] + a[3];
      s[3] += a[2] + a[3] + ra;
      w[0] += lb + bb4[0] + bb4[1];
      w[1] += bb4[0] + bb4[1] + bb4[2];
      w[2] += bb4[1] + bb4[2] + bb4[3];
      w[3] += bb4[2] + bb4[3] + rb;
    }
#pragma unroll
    for (int i = 0; i < 4; ++i)
      acc[i] += LN2 * __builtin_amdgcn_logf(s[i]) - w[i] * __builtin_amdgcn_rcpf(s[i]);

    if (cc < 7) {
      vbuf[0] = vnext[0];
      vbuf[1] = vnext[1];
      vbuf[2] = vnext[2];
    }
  }

  // Reduce the 8 channel groups (8 KiB LDS).
  __shared__ float red[8][4][64];
#pragma unroll
  for (int i = 0; i < 4; ++i) red[ty][i][tx] = acc[i];
  __syncthreads();
  if (ty == 0) {
    float4 o;
    float* op = &o.x;
    float mn = INFINITY, mx = -INFINITY;
#pragma unroll
    for (int i = 0; i < 4; ++i) {
      float v = 0.f;
#pragma unroll
      for (int g = 0; g < 8; ++g) v += red[g][i][tx];
      v *= (1.0f / Cc);
      op[i] = v;
      mn = fminf(mn, v);
      mx = fmaxf(mx, v);
    }
    *reinterpret_cast<float4*>(e + (size_t)(b * Hh + h) * Ww + w0) = o;

#pragma unroll
    for (int off = 32; off > 0; off >>= 1) {
      mn = fminf(mn, __shfl_down(mn, off, 64));
      mx = fmaxf(mx, __shfl_down(mx, off, 64));
    }
    if (tx == 0) {
      atomicMin(&stats[b], fenc(mn));
      atomicMax(&stats[4 + b], fenc(mx));
    }
  }
}

// In-place normalize d_out. 65536 threads, 4 elements each (float4).
__global__ __launch_bounds__(256) void norm_kernel(float* __restrict__ e,
                                                   const unsigned int* __restrict__ stats) {
  const int t = blockIdx.x * 256 + threadIdx.x;           // 0..65535
  const int b = t >> 14;                                  // (t*4) >> 16
  const float mn = fdec(stats[b]);
  const float mx = fdec(stats[4 + b]);
  const float inv = 1.0f / fmaxf(mx - mn, 1e-6f);
  float4 v = reinterpret_cast<float4*>(e)[t];
  v.x = (v.x - mn) * inv;
  v.y = (v.y - mn) * inv;
  v.z = (v.z - mn) * inv;
  v.w = (v.w - mn) * inv;
  reinterpret_cast<float4*>(e)[t] = v;
}

extern "C" void kernel_launch(void* const* d_in, const int* in_sizes, int n_in,
                              void* d_out, int out_size, void* d_ws, size_t ws_size,
                              hipStream_t stream) {
  const float* x = (const float*)d_in[0];
  float* out = (float*)d_out;                 // e, then normalized in place
  unsigned int* stats = (unsigned int*)d_ws;  // 8 uints

  // Init: min keys -> 0xFFFFFFFF, max keys -> 0.
  hipMemsetAsync(stats, 0xFF, 4 * sizeof(unsigned int), stream);
  hipMemsetAsync(stats + 4, 0x00, 4 * sizeof(unsigned int), stream);

  entropy_kernel<<<dim3(Bb * Hh), dim3(64, 8), 0, stream>>>(x, out, stats);
  norm_kernel<<<dim3((Bb * Hh * Ww / 4) / 256), dim3(256), 0, stream>>>(out, stats);
}

// Round 8
// 62.571 us; speedup vs baseline: 3.2866x; 1.7392x over previous
//
#include <hip/hip_runtime.h>
#include <math.h>

constexpr int Bb = 4, Cc = 64, Hh = 256, Ww = 256;

#define LOG2E 1.44269504088896340736f
#define LN2   0.69314718055994530942f

__device__ __forceinline__ unsigned int fenc(float f) {
  unsigned int u = __float_as_uint(f);
  return (u & 0x80000000u) ? ~u : (u | 0x80000000u);
}
__device__ __forceinline__ float fdec(unsigned int k) {
  return __uint_as_float((k & 0x80000000u) ? (k ^ 0x80000000u) : ~k);
}

// entropy = ln(s) - ws/s, s = 3x3 box of e^v, ws = 3x3 box of v*e^v
// (shift-invariant softmax entropy; N(0,1) inputs so e^v safe in fp32).
// Zero-padding contributes a=1, b=0 == exp of a loaded 0.
//
// Grid: B*H = 1024 blocks (one output row each). Block (64,8): ty = 8
// channels each, thread = 4 cols (float4). Channel loop double-buffered.
// NOTE: do NOT pass a min-waves arg to __launch_bounds__ — both (512,8)
// (r6: VGPR 32) and (512,4) (r7: VGPR 64) made the allocator spill
// (~190-360MB scratch traffic, 2-4x slowdown). Plain (512) gives ~52-60
// VGPR spill-free (r5), which already permits 8 waves/SIMD.
__global__ __launch_bounds__(512) void entropy_kernel(const float* __restrict__ x,
                                                      float* __restrict__ e,
                                                      unsigned int* __restrict__ stats) {
  const int b = blockIdx.x >> 8;          // / Hh
  const int h = blockIdx.x & (Hh - 1);
  const int tx = threadIdx.x;             // 0..63
  const int ty = threadIdx.y;             // 0..7
  const int w0 = tx * 4;

  const size_t planeStride = (size_t)Hh * Ww;
  const float* xb = x + ((size_t)b * Cc + (size_t)ty * 8) * planeStride + w0;
  const bool up_ok = (h > 0), dn_ok = (h < Hh - 1);
  const size_t rowUp = (size_t)(h - 1) * Ww;
  const size_t rowMd = (size_t)h * Ww;
  const size_t rowDn = (size_t)(h + 1) * Ww;

  float acc[4] = {0.f, 0.f, 0.f, 0.f};

  float4 vbuf[3];
  vbuf[0] = up_ok ? *reinterpret_cast<const float4*>(xb + rowUp) : make_float4(0.f, 0.f, 0.f, 0.f);
  vbuf[1] = *reinterpret_cast<const float4*>(xb + rowMd);
  vbuf[2] = dn_ok ? *reinterpret_cast<const float4*>(xb + rowDn) : make_float4(0.f, 0.f, 0.f, 0.f);

  for (int cc = 0; cc < 8; ++cc) {
    float4 vnext[3];
    if (cc < 7) {
      const float* p = xb + (size_t)(cc + 1) * planeStride;
      vnext[0] = up_ok ? *reinterpret_cast<const float4*>(p + rowUp) : make_float4(0.f, 0.f, 0.f, 0.f);
      vnext[1] = *reinterpret_cast<const float4*>(p + rowMd);
      vnext[2] = dn_ok ? *reinterpret_cast<const float4*>(p + rowDn) : make_float4(0.f, 0.f, 0.f, 0.f);
    }

    float s[4] = {0.f, 0.f, 0.f, 0.f};
    float w[4] = {0.f, 0.f, 0.f, 0.f};
#pragma unroll
    for (int j = 0; j < 3; ++j) {
      const float* vp = &vbuf[j].x;
      float a[4], bb4[4];
#pragma unroll
      for (int i = 0; i < 4; ++i) {
        float t = __builtin_amdgcn_exp2f(vp[i] * LOG2E);  // e^v
        a[i] = t;
        bb4[i] = vp[i] * t;                               // v * e^v
      }
      float la = __shfl_up(a[3], 1, 64);
      float lb = __shfl_up(bb4[3], 1, 64);
      float ra = __shfl_down(a[0], 1, 64);
      float rb = __shfl_down(bb4[0], 1, 64);
      la = (tx == 0) ? 1.f : la;   lb = (tx == 0) ? 0.f : lb;
      ra = (tx == 63) ? 1.f : ra;  rb = (tx == 63) ? 0.f : rb;
      s[0] += la + a[0] + a[1];
      s[1] += a[0] + a[1] + a[2];
      s[2] += a[1] + a[2] + a[3];
      s[3] += a[2] + a[3] + ra;
      w[0] += lb + bb4[0] + bb4[1];
      w[1] += bb4[0] + bb4[1] + bb4[2];
      w[2] += bb4[1] + bb4[2] + bb4[3];
      w[3] += bb4[2] + bb4[3] + rb;
    }
#pragma unroll
    for (int i = 0; i < 4; ++i)
      acc[i] += LN2 * __builtin_amdgcn_logf(s[i]) - w[i] * __builtin_amdgcn_rcpf(s[i]);

    if (cc < 7) {
      vbuf[0] = vnext[0];
      vbuf[1] = vnext[1];
      vbuf[2] = vnext[2];
    }
  }

  // Reduce the 8 channel groups (8 KiB LDS).
  __shared__ float red[8][4][64];
#pragma unroll
  for (int i = 0; i < 4; ++i) red[ty][i][tx] = acc[i];
  __syncthreads();
  if (ty == 0) {
    float4 o;
    float* op = &o.x;
    float mn = INFINITY, mx = -INFINITY;
#pragma unroll
    for (int i = 0; i < 4; ++i) {
      float v = 0.f;
#pragma unroll
      for (int g = 0; g < 8; ++g) v += red[g][i][tx];
      v *= (1.0f / Cc);
      op[i] = v;
      mn = fminf(mn, v);
      mx = fmaxf(mx, v);
    }
    *reinterpret_cast<float4*>(e + (size_t)(b * Hh + h) * Ww + w0) = o;

#pragma unroll
    for (int off = 32; off > 0; off >>= 1) {
      mn = fminf(mn, __shfl_down(mn, off, 64));
      mx = fmaxf(mx, __shfl_down(mx, off, 64));
    }
    if (tx == 0) {
      atomicMin(&stats[b], fenc(mn));
      atomicMax(&stats[4 + b], fenc(mx));
    }
  }
}

// In-place normalize d_out. 65536 threads, 4 elements each (float4).
__global__ __launch_bounds__(256) void norm_kernel(float* __restrict__ e,
                                                   const unsigned int* __restrict__ stats) {
  const int t = blockIdx.x * 256 + threadIdx.x;           // 0..65535
  const int b = t >> 14;                                  // (t*4) >> 16
  const float mn = fdec(stats[b]);
  const float mx = fdec(stats[4 + b]);
  const float inv = 1.0f / fmaxf(mx - mn, 1e-6f);
  float4 v = reinterpret_cast<float4*>(e)[t];
  v.x = (v.x - mn) * inv;
  v.y = (v.y - mn) * inv;
  v.z = (v.z - mn) * inv;
  v.w = (v.w - mn) * inv;
  reinterpret_cast<float4*>(e)[t] = v;
}

extern "C" void kernel_launch(void* const* d_in, const int* in_sizes, int n_in,
                              void* d_out, int out_size, void* d_ws, size_t ws_size,
                              hipStream_t stream) {
  const float* x = (const float*)d_in[0];
  float* out = (float*)d_out;                 // e, then normalized in place
  unsigned int* stats = (unsigned int*)d_ws;  // 8 uints

  // Init: min keys -> 0xFFFFFFFF, max keys -> 0.
  hipMemsetAsync(stats, 0xFF, 4 * sizeof(unsigned int), stream);
  hipMemsetAsync(stats + 4, 0x00, 4 * sizeof(unsigned int), stream);

  entropy_kernel<<<dim3(Bb * Hh), dim3(64, 8), 0, stream>>>(x, out, stats);
  norm_kernel<<<dim3((Bb * Hh * Ww / 4) / 256), dim3(256), 0, stream>>>(out, stats);
}

// Round 9
// 49.512 us; speedup vs baseline: 4.1534x; 1.2638x over previous
//
#include <hip/hip_runtime.h>
#include <math.h>

constexpr int Bb = 4, Cc = 64, Hh = 256, Ww = 256;
constexpr int RR = 2;            // output rows per block
constexpr int CS = 2;            // channel split factor (32 ch per block)
constexpr int NSTRIP = Hh / RR;  // 128

#define LOG2E 1.44269504088896340736f
#define LN2   0.69314718055994530942f

__device__ __forceinline__ unsigned int fenc(float f) {
  unsigned int u = __float_as_uint(f);
  return (u & 0x80000000u) ? ~u : (u | 0x80000000u);
}
__device__ __forceinline__ float fdec(unsigned int k) {
  return __uint_as_float((k & 0x80000000u) ? (k ^ 0x80000000u) : ~k);
}

// entropy = ln(s) - ws/s, s = 3x3 box of e^v, ws = 3x3 box of v*e^v
// (shift-invariant softmax entropy; N(0,1) inputs so e^v safe in fp32).
// Final normalize is invariant to positive affine maps of e, so we keep raw
// channel SUMS (no /64) and normalize those.
//
// Grid: b(4) x strip(128) x cs(2) = 1024 blocks, block (64,8) -> 8192 waves
// (full chip at <=64 VGPR). Each block: 2 output rows x 32 channels
// (ty covers 4 each, rolled cc loop). Channel-halves combine by atomicAdd
// into e (memset to 0 first). NOTE: plain __launch_bounds__(512) only —
// any min-waves hint spilled (r6: 300MB, r7: 187MB scratch traffic).
__global__ __launch_bounds__(512) void entropy_kernel(const float* __restrict__ x,
                                                      float* __restrict__ e) {
  const int bx = blockIdx.x;
  const int cs = bx & 1;
  const int strip = (bx >> 1) & (NSTRIP - 1);
  const int b = bx >> 8;
  const int r0 = strip * RR;
  const int tx = threadIdx.x;   // 0..63
  const int ty = threadIdx.y;   // 0..7
  const int w0 = tx * 4;

  const size_t planeStride = (size_t)Hh * Ww;
  const float* xb = x + ((size_t)b * Cc + cs * 32 + ty * 4) * planeStride + w0;

  float acc[RR][4];
#pragma unroll
  for (int o = 0; o < RR; ++o)
#pragma unroll
    for (int i = 0; i < 4; ++i) acc[o][i] = 0.f;

#pragma unroll 1
  for (int cc = 0; cc < 4; ++cc) {
    const float* plane = xb + (size_t)cc * planeStride;

    // Preload the RR+2 = 4 rows (4 outstanding dwordx4 loads).
    float4 v[RR + 2];
#pragma unroll
    for (int j = 0; j < RR + 2; ++j) {
      const int row = r0 - 1 + j;
      if (row >= 0 && row < Hh)
        v[j] = *reinterpret_cast<const float4*>(plane + (size_t)row * Ww);
      else
        v[j] = make_float4(0.f, 0.f, 0.f, 0.f);
    }

    float s[RR][4], w[RR][4];
#pragma unroll
    for (int o = 0; o < RR; ++o)
#pragma unroll
      for (int i = 0; i < 4; ++i) { s[o][i] = 0.f; w[o][i] = 0.f; }

#pragma unroll
    for (int j = 0; j < RR + 2; ++j) {
      const float* vp = &v[j].x;
      float a[4], bb4[4];
#pragma unroll
      for (int i = 0; i < 4; ++i) {
        float t = __builtin_amdgcn_exp2f(vp[i] * LOG2E);  // e^v
        a[i] = t;
        bb4[i] = vp[i] * t;                               // v * e^v
      }
      float la = __shfl_up(a[3], 1, 64);
      float lb = __shfl_up(bb4[3], 1, 64);
      float ra = __shfl_down(a[0], 1, 64);
      float rb = __shfl_down(bb4[0], 1, 64);
      la = (tx == 0) ? 1.f : la;   lb = (tx == 0) ? 0.f : lb;
      ra = (tx == 63) ? 1.f : ra;  rb = (tx == 63) ? 0.f : rb;
      float ha[4], hb[4];
      ha[0] = la + a[0] + a[1];
      ha[1] = a[0] + a[1] + a[2];
      ha[2] = a[1] + a[2] + a[3];
      ha[3] = a[2] + a[3] + ra;
      hb[0] = lb + bb4[0] + bb4[1];
      hb[1] = bb4[0] + bb4[1] + bb4[2];
      hb[2] = bb4[1] + bb4[2] + bb4[3];
      hb[3] = bb4[2] + bb4[3] + rb;
      // Row j contributes to output rows o with o <= j <= o+2.
#pragma unroll
      for (int o = 0; o < RR; ++o) {
        if (j >= o && j <= o + 2) {
#pragma unroll
          for (int i = 0; i < 4; ++i) { s[o][i] += ha[i]; w[o][i] += hb[i]; }
        }
      }
    }
#pragma unroll
    for (int o = 0; o < RR; ++o)
#pragma unroll
      for (int i = 0; i < 4; ++i)
        acc[o][i] += LN2 * __builtin_amdgcn_logf(s[o][i]) -
                     w[o][i] * __builtin_amdgcn_rcpf(s[o][i]);
  }

  // Reduce the 8 ty channel groups (16 KiB LDS), then atomicAdd the
  // channel-half partial into e.
  __shared__ float red[8][RR][4][64];
#pragma unroll
  for (int o = 0; o < RR; ++o)
#pragma unroll
    for (int i = 0; i < 4; ++i) red[ty][o][i][tx] = acc[o][i];
  __syncthreads();
  if (ty < RR) {
    const int o = ty;
    float* ep = e + (size_t)(b * Hh + r0 + o) * Ww + w0;
#pragma unroll
    for (int i = 0; i < 4; ++i) {
      float vsum = 0.f;
#pragma unroll
      for (int g = 0; g < 8; ++g) vsum += red[g][o][i][tx];
      atomicAdd(ep + i, vsum);
    }
  }
}

// Per-batch min/max of e. Grid 256: batch = bx>>6, chunk = bx&63 (1024
// floats each, thread reads one float4).
__global__ __launch_bounds__(256) void minmax_kernel(const float* __restrict__ e,
                                                     unsigned int* __restrict__ stats) {
  const int bx = blockIdx.x;
  const int b = bx >> 6;
  const int chunk = bx & 63;
  const float4 v = reinterpret_cast<const float4*>(
      e + (size_t)b * Hh * Ww + chunk * 1024)[threadIdx.x];
  float mn = fminf(fminf(v.x, v.y), fminf(v.z, v.w));
  float mx = fmaxf(fmaxf(v.x, v.y), fmaxf(v.z, v.w));
#pragma unroll
  for (int off = 32; off > 0; off >>= 1) {
    mn = fminf(mn, __shfl_down(mn, off, 64));
    mx = fmaxf(mx, __shfl_down(mx, off, 64));
  }
  __shared__ float smn[4], smx[4];
  const int wave = threadIdx.x >> 6;
  if ((threadIdx.x & 63) == 0) { smn[wave] = mn; smx[wave] = mx; }
  __syncthreads();
  if (threadIdx.x == 0) {
    mn = fminf(fminf(smn[0], smn[1]), fminf(smn[2], smn[3]));
    mx = fmaxf(fmaxf(smx[0], smx[1]), fmaxf(smx[2], smx[3]));
    atomicMin(&stats[b], fenc(mn));
    atomicMax(&stats[4 + b], fenc(mx));
  }
}

// In-place normalize d_out. 65536 threads, 1 float4 each.
__global__ __launch_bounds__(256) void norm_kernel(float* __restrict__ e,
                                                   const unsigned int* __restrict__ stats) {
  const int t = blockIdx.x * 256 + threadIdx.x;           // 0..65535
  const int b = t >> 14;
  const float mn = fdec(stats[b]);
  const float mx = fdec(stats[4 + b]);
  const float inv = 1.0f / fmaxf(mx - mn, 1e-6f);
  float4 v = reinterpret_cast<float4*>(e)[t];
  v.x = (v.x - mn) * inv;
  v.y = (v.y - mn) * inv;
  v.z = (v.z - mn) * inv;
  v.w = (v.w - mn) * inv;
  reinterpret_cast<float4*>(e)[t] = v;
}

extern "C" void kernel_launch(void* const* d_in, const int* in_sizes, int n_in,
                              void* d_out, int out_size, void* d_ws, size_t ws_size,
                              hipStream_t stream) {
  const float* x = (const float*)d_in[0];
  float* out = (float*)d_out;                 // raw sums, then normalized
  unsigned int* stats = (unsigned int*)d_ws;  // 8 uints

  // e := 0 (atomicAdd target), stats := {min: 0xFF.., max: 0}.
  hipMemsetAsync(out, 0, (size_t)Bb * Hh * Ww * sizeof(float), stream);
  hipMemsetAsync(stats, 0xFF, 4 * sizeof(unsigned int), stream);
  hipMemsetAsync(stats + 4, 0x00, 4 * sizeof(unsigned int), stream);

  entropy_kernel<<<dim3(Bb * NSTRIP * CS), dim3(64, 8), 0, stream>>>(x, out);
  minmax_kernel<<<dim3(Bb * 64), dim3(256), 0, stream>>>(out, stats);
  norm_kernel<<<dim3((Bb * Hh * Ww / 4) / 256), dim3(256), 0, stream>>>(out, stats);
}

// Round 10
// 33.546 us; speedup vs baseline: 6.1303x; 1.4760x over previous
//
#include <hip/hip_runtime.h>
#include <math.h>

constexpr int Bb = 4, Cc = 64, Hh = 256, Ww = 256;
constexpr int RR = 2;            // output rows per block
constexpr int NSTRIP = Hh / RR;  // 128
constexpr int NPX = Bb * Hh * Ww;       // 262144 output pixels
constexpr int NPX4 = NPX / 4;           // 65536 float4s

#define LOG2E 1.44269504088896340736f
#define LN2   0.69314718055994530942f

__device__ __forceinline__ unsigned int fenc(float f) {
  unsigned int u = __float_as_uint(f);
  return (u & 0x80000000u) ? ~u : (u | 0x80000000u);
}
__device__ __forceinline__ float fdec(unsigned int k) {
  return __uint_as_float((k & 0x80000000u) ? (k ^ 0x80000000u) : ~k);
}

// entropy = ln(s) - ws/s, s = 3x3 box of e^v, ws = 3x3 box of v*e^v
// (shift-invariant softmax entropy; N(0,1) inputs so e^v safe in fp32).
// Final normalize is invariant to positive affine maps, so raw channel sums
// (no /64) are normalized directly.
//
// Grid: b(4) x strip(128) x cs(2) = 1024 blocks, block (64,8) -> 8192 waves.
// Each block: RR=2 output rows x 32 channels (ty covers 4, rolled cc loop).
// DST selects the output pointer arithmetic:
//   DST=0: non-atomic store of the channel-half partial into pw[cs][...]
//   DST=1: atomicAdd into e (fallback when ws too small; e pre-zeroed)
// NOTE: plain __launch_bounds__(512) only — any min-waves hint spills
// (r6: 300MB, r7: 187MB scratch traffic).
template <int DST>
__global__ __launch_bounds__(512) void entropy_kernel(const float* __restrict__ x,
                                                      float* __restrict__ out) {
  const int bx = blockIdx.x;
  const int cs = bx & 1;
  const int strip = (bx >> 1) & (NSTRIP - 1);
  const int b = bx >> 8;
  const int r0 = strip * RR;
  const int tx = threadIdx.x;   // 0..63
  const int ty = threadIdx.y;   // 0..7
  const int w0 = tx * 4;

  const size_t planeStride = (size_t)Hh * Ww;
  const float* xb = x + ((size_t)b * Cc + cs * 32 + ty * 4) * planeStride + w0;

  float acc[RR][4];
#pragma unroll
  for (int o = 0; o < RR; ++o)
#pragma unroll
    for (int i = 0; i < 4; ++i) acc[o][i] = 0.f;

#pragma unroll 1
  for (int cc = 0; cc < 4; ++cc) {
    const float* plane = xb + (size_t)cc * planeStride;

    float4 v[RR + 2];
#pragma unroll
    for (int j = 0; j < RR + 2; ++j) {
      const int row = r0 - 1 + j;
      if (row >= 0 && row < Hh)
        v[j] = *reinterpret_cast<const float4*>(plane + (size_t)row * Ww);
      else
        v[j] = make_float4(0.f, 0.f, 0.f, 0.f);
    }

    float s[RR][4], w[RR][4];
#pragma unroll
    for (int o = 0; o < RR; ++o)
#pragma unroll
      for (int i = 0; i < 4; ++i) { s[o][i] = 0.f; w[o][i] = 0.f; }

#pragma unroll
    for (int j = 0; j < RR + 2; ++j) {
      const float* vp = &v[j].x;
      float a[4], bb4[4];
#pragma unroll
      for (int i = 0; i < 4; ++i) {
        float t = __builtin_amdgcn_exp2f(vp[i] * LOG2E);  // e^v
        a[i] = t;
        bb4[i] = vp[i] * t;                               // v * e^v
      }
      float la = __shfl_up(a[3], 1, 64);
      float lb = __shfl_up(bb4[3], 1, 64);
      float ra = __shfl_down(a[0], 1, 64);
      float rb = __shfl_down(bb4[0], 1, 64);
      la = (tx == 0) ? 1.f : la;   lb = (tx == 0) ? 0.f : lb;
      ra = (tx == 63) ? 1.f : ra;  rb = (tx == 63) ? 0.f : rb;
      float ha[4], hb[4];
      ha[0] = la + a[0] + a[1];
      ha[1] = a[0] + a[1] + a[2];
      ha[2] = a[1] + a[2] + a[3];
      ha[3] = a[2] + a[3] + ra;
      hb[0] = lb + bb4[0] + bb4[1];
      hb[1] = bb4[0] + bb4[1] + bb4[2];
      hb[2] = bb4[1] + bb4[2] + bb4[3];
      hb[3] = bb4[2] + bb4[3] + rb;
#pragma unroll
      for (int o = 0; o < RR; ++o) {
        if (j >= o && j <= o + 2) {
#pragma unroll
          for (int i = 0; i < 4; ++i) { s[o][i] += ha[i]; w[o][i] += hb[i]; }
        }
      }
    }
#pragma unroll
    for (int o = 0; o < RR; ++o)
#pragma unroll
      for (int i = 0; i < 4; ++i)
        acc[o][i] += LN2 * __builtin_amdgcn_logf(s[o][i]) -
                     w[o][i] * __builtin_amdgcn_rcpf(s[o][i]);
  }

  __shared__ float red[8][RR][4][64];
#pragma unroll
  for (int o = 0; o < RR; ++o)
#pragma unroll
    for (int i = 0; i < 4; ++i) red[ty][o][i][tx] = acc[o][i];
  __syncthreads();
  if (ty < RR) {
    const int o = ty;
    const size_t px = (size_t)(b * Hh + r0 + o) * Ww + w0;
    float vsum[4];
#pragma unroll
    for (int i = 0; i < 4; ++i) {
      float t = 0.f;
#pragma unroll
      for (int g = 0; g < 8; ++g) t += red[g][o][i][tx];
      vsum[i] = t;
    }
    if (DST == 0) {
      float4 o4 = make_float4(vsum[0], vsum[1], vsum[2], vsum[3]);
      *reinterpret_cast<float4*>(out + (size_t)cs * NPX + px) = o4;
    } else {
#pragma unroll
      for (int i = 0; i < 4; ++i) atomicAdd(out + px + i, vsum[i]);
    }
  }
}

// ws path K2: combine the two channel-half partials, write e, and emit
// per-block min/max partials (every slot written -> no init needed).
// Grid 256 x 256 threads, one float4 per thread. Batch = bx>>6.
__global__ __launch_bounds__(256) void combine_minmax(const float* __restrict__ pw,
                                                      float* __restrict__ e,
                                                      float* __restrict__ pm) {
  const int t = blockIdx.x * 256 + threadIdx.x;
  float4 a = reinterpret_cast<const float4*>(pw)[t];
  float4 c = reinterpret_cast<const float4*>(pw + NPX)[t];
  float4 v = make_float4(a.x + c.x, a.y + c.y, a.z + c.z, a.w + c.w);
  reinterpret_cast<float4*>(e)[t] = v;

  float mn = fminf(fminf(v.x, v.y), fminf(v.z, v.w));
  float mx = fmaxf(fmaxf(v.x, v.y), fmaxf(v.z, v.w));
#pragma unroll
  for (int off = 32; off > 0; off >>= 1) {
    mn = fminf(mn, __shfl_down(mn, off, 64));
    mx = fmaxf(mx, __shfl_down(mx, off, 64));
  }
  __shared__ float smn[4], smx[4];
  const int wave = threadIdx.x >> 6;
  if ((threadIdx.x & 63) == 0) { smn[wave] = mn; smx[wave] = mx; }
  __syncthreads();
  if (threadIdx.x == 0) {
    pm[blockIdx.x]       = fminf(fminf(smn[0], smn[1]), fminf(smn[2], smn[3]));
    pm[256 + blockIdx.x] = fmaxf(fmaxf(smx[0], smx[1]), fmaxf(smx[2], smx[3]));
  }
}

// ws path K3: reduce this batch's 64 min/max partials in-wave (redundant per
// wave, cheap), then normalize. Grid 256 x 256, one float4 per thread.
__global__ __launch_bounds__(256) void norm_ws(float* __restrict__ e,
                                               const float* __restrict__ pm) {
  const int b = blockIdx.x >> 6;
  const int lane = threadIdx.x & 63;
  float mn = pm[b * 64 + lane];
  float mx = pm[256 + b * 64 + lane];
#pragma unroll
  for (int off = 32; off > 0; off >>= 1) {
    mn = fminf(mn, __shfl_down(mn, off, 64));
    mx = fmaxf(mx, __shfl_down(mx, off, 64));
  }
  mn = __shfl(mn, 0, 64);
  mx = __shfl(mx, 0, 64);
  const float inv = 1.0f / fmaxf(mx - mn, 1e-6f);

  const int t = blockIdx.x * 256 + threadIdx.x;
  float4 v = reinterpret_cast<float4*>(e)[t];
  v.x = (v.x - mn) * inv;
  v.y = (v.y - mn) * inv;
  v.z = (v.z - mn) * inv;
  v.w = (v.w - mn) * inv;
  reinterpret_cast<float4*>(e)[t] = v;
}

// Fallback path kernels (atomics + memset) — used only if ws is tiny.
__global__ __launch_bounds__(256) void minmax_atomic(const float* __restrict__ e,
                                                     unsigned int* __restrict__ stats) {
  const int bx = blockIdx.x;
  const int b = bx >> 6;
  const float4 v = reinterpret_cast<const float4*>(
      e + (size_t)b * Hh * Ww + (bx & 63) * 1024)[threadIdx.x];
  float mn = fminf(fminf(v.x, v.y), fminf(v.z, v.w));
  float mx = fmaxf(fmaxf(v.x, v.y), fmaxf(v.z, v.w));
#pragma unroll
  for (int off = 32; off > 0; off >>= 1) {
    mn = fminf(mn, __shfl_down(mn, off, 64));
    mx = fmaxf(mx, __shfl_down(mx, off, 64));
  }
  __shared__ float smn[4], smx[4];
  const int wave = threadIdx.x >> 6;
  if ((threadIdx.x & 63) == 0) { smn[wave] = mn; smx[wave] = mx; }
  __syncthreads();
  if (threadIdx.x == 0) {
    atomicMin(&stats[b], fenc(fminf(fminf(smn[0], smn[1]), fminf(smn[2], smn[3]))));
    atomicMax(&stats[4 + b], fenc(fmaxf(fmaxf(smx[0], smx[1]), fmaxf(smx[2], smx[3]))));
  }
}

__global__ __launch_bounds__(256) void norm_atomic(float* __restrict__ e,
                                                   const unsigned int* __restrict__ stats) {
  const int t = blockIdx.x * 256 + threadIdx.x;
  const int b = t >> 14;
  const float mn = fdec(stats[b]);
  const float mx = fdec(stats[4 + b]);
  const float inv = 1.0f / fmaxf(mx - mn, 1e-6f);
  float4 v = reinterpret_cast<float4*>(e)[t];
  v.x = (v.x - mn) * inv;
  v.y = (v.y - mn) * inv;
  v.z = (v.z - mn) * inv;
  v.w = (v.w - mn) * inv;
  reinterpret_cast<float4*>(e)[t] = v;
}

extern "C" void kernel_launch(void* const* d_in, const int* in_sizes, int n_in,
                              void* d_out, int out_size, void* d_ws, size_t ws_size,
                              hipStream_t stream) {
  const float* x = (const float*)d_in[0];
  float* out = (float*)d_out;

  const size_t ws_needed = (size_t)(2 * NPX + 512) * sizeof(float);  // ~2.1 MB
  if (ws_size >= ws_needed) {
    float* pw = (float*)d_ws;            // [2][NPX] channel-half partials
    float* pm = pw + 2 * NPX;            // [256 min][256 max] block partials
    entropy_kernel<0><<<dim3(Bb * NSTRIP * 2), dim3(64, 8), 0, stream>>>(x, pw);
    combine_minmax<<<dim3(NPX4 / 256), dim3(256), 0, stream>>>(pw, out, pm);
    norm_ws<<<dim3(NPX4 / 256), dim3(256), 0, stream>>>(out, pm);
  } else {
    unsigned int* stats = (unsigned int*)d_ws;  // 8 uints
    hipMemsetAsync(out, 0, (size_t)NPX * sizeof(float), stream);
    hipMemsetAsync(stats, 0xFF, 4 * sizeof(unsigned int), stream);
    hipMemsetAsync(stats + 4, 0x00, 4 * sizeof(unsigned int), stream);
    entropy_kernel<1><<<dim3(Bb * NSTRIP * 2), dim3(64, 8), 0, stream>>>(x, out);
    minmax_atomic<<<dim3(Bb * 64), dim3(256), 0, stream>>>(out, stats);
    norm_atomic<<<dim3(NPX4 / 256), dim3(256), 0, stream>>>(out, stats);
  }
}

// Round 11
// 28.065 us; speedup vs baseline: 7.3274x; 1.1953x over previous
//
#include <hip/hip_runtime.h>
#include <math.h>

constexpr int Bb = 4, Cc = 64, Hh = 256, Ww = 256;
constexpr int RR = 4;            // output rows per block
constexpr int CS = 4;            // channel split (16 ch per block)
constexpr int NSTRIP = Hh / RR;  // 64
constexpr int NPX = Bb * Hh * Ww;       // 262144 output pixels
constexpr int NPX4 = NPX / 4;           // 65536 float4s

#define LOG2E 1.44269504088896340736f
#define LN2   0.69314718055994530942f

__device__ __forceinline__ unsigned int fenc(float f) {
  unsigned int u = __float_as_uint(f);
  return (u & 0x80000000u) ? ~u : (u | 0x80000000u);
}
__device__ __forceinline__ float fdec(unsigned int k) {
  return __uint_as_float((k & 0x80000000u) ? (k ^ 0x80000000u) : ~k);
}

// entropy = ln(s) - ws/s, s = 3x3 box of e^v, ws = 3x3 box of v*e^v
// (shift-invariant softmax entropy; N(0,1) inputs so e^v safe in fp32).
// Normalization is affine-invariant, so raw channel sums are normalized.
//
// Grid: b(4) x strip(64) x cs(4) = 1024 blocks, block (64,8) -> 8192 waves.
// Each block: RR=4 output rows x 16 channels (2 per ty, rolled cc loop).
// Halo amplification (RR+2)/RR = 1.5x (vs 2.0x at RR=2) — 25% less exp work.
// 3-slot ring of horizontal sums (round-5-proven shape, 52 VGPR there).
//   DST=0: non-atomic store of channel-quarter partial into pw[cs][...]
//   DST=1: atomicAdd into e (fallback; e pre-zeroed)
// NOTE: plain __launch_bounds__(512) only — min-waves hints spill (r6/r7).
template <int DST>
__global__ __launch_bounds__(512) void entropy_kernel(const float* __restrict__ x,
                                                      float* __restrict__ out) {
  const int bx = blockIdx.x;
  const int cs = bx & 3;
  const int strip = (bx >> 2) & (NSTRIP - 1);
  const int b = bx >> 8;
  const int r0 = strip * RR;
  const int tx = threadIdx.x;   // 0..63
  const int ty = threadIdx.y;   // 0..7
  const int w0 = tx * 4;

  const size_t planeStride = (size_t)Hh * Ww;
  const float* xb = x + ((size_t)b * Cc + cs * 16 + ty * 2) * planeStride + w0;

  float acc[RR][4];
#pragma unroll
  for (int o = 0; o < RR; ++o)
#pragma unroll
    for (int i = 0; i < 4; ++i) acc[o][i] = 0.f;

#pragma unroll 1
  for (int cc = 0; cc < 2; ++cc) {
    const float* plane = xb + (size_t)cc * planeStride;

    // Preload the RR+2 = 6 strip rows (6 outstanding dwordx4 loads).
    float4 v[RR + 2];
#pragma unroll
    for (int j = 0; j < RR + 2; ++j) {
      const int row = r0 - 1 + j;
      if (row >= 0 && row < Hh)
        v[j] = *reinterpret_cast<const float4*>(plane + (size_t)row * Ww);
      else
        v[j] = make_float4(0.f, 0.f, 0.f, 0.f);
    }

    float ha[3][4], hb[3][4];
#pragma unroll
    for (int j = 0; j < RR + 2; ++j) {
      const float* vp = &v[j].x;
      float a[4], bb4[4];
#pragma unroll
      for (int i = 0; i < 4; ++i) {
        float t = __builtin_amdgcn_exp2f(vp[i] * LOG2E);  // e^v
        a[i] = t;
        bb4[i] = vp[i] * t;                               // v * e^v
      }
      float la = __shfl_up(a[3], 1, 64);
      float lb = __shfl_up(bb4[3], 1, 64);
      float ra = __shfl_down(a[0], 1, 64);
      float rb = __shfl_down(bb4[0], 1, 64);
      la = (tx == 0) ? 1.f : la;   lb = (tx == 0) ? 0.f : lb;
      ra = (tx == 63) ? 1.f : ra;  rb = (tx == 63) ? 0.f : rb;
      const int s0 = j % 3;  // compile-time (loop unrolled)
      ha[s0][0] = la + a[0] + a[1];
      ha[s0][1] = a[0] + a[1] + a[2];
      ha[s0][2] = a[1] + a[2] + a[3];
      ha[s0][3] = a[2] + a[3] + ra;
      hb[s0][0] = lb + bb4[0] + bb4[1];
      hb[s0][1] = bb4[0] + bb4[1] + bb4[2];
      hb[s0][2] = bb4[1] + bb4[2] + bb4[3];
      hb[s0][3] = bb4[2] + bb4[3] + rb;
      if (j >= 2) {
        const int orow = j - 2;
#pragma unroll
        for (int i = 0; i < 4; ++i) {
          float s = ha[0][i] + ha[1][i] + ha[2][i];
          float w = hb[0][i] + hb[1][i] + hb[2][i];
          acc[orow][i] += LN2 * __builtin_amdgcn_logf(s) -
                          w * __builtin_amdgcn_rcpf(s);
        }
      }
    }
  }

  // Reduce the 8 ty groups (32 KiB LDS).
  __shared__ float red[8][RR][4][64];
#pragma unroll
  for (int o = 0; o < RR; ++o)
#pragma unroll
    for (int i = 0; i < 4; ++i) red[ty][o][i][tx] = acc[o][i];
  __syncthreads();
  if (ty < RR) {
    const int o = ty;
    const size_t px = (size_t)(b * Hh + r0 + o) * Ww + w0;
    float vsum[4];
#pragma unroll
    for (int i = 0; i < 4; ++i) {
      float t = 0.f;
#pragma unroll
      for (int g = 0; g < 8; ++g) t += red[g][o][i][tx];
      vsum[i] = t;
    }
    if (DST == 0) {
      *reinterpret_cast<float4*>(out + (size_t)cs * NPX + px) =
          make_float4(vsum[0], vsum[1], vsum[2], vsum[3]);
    } else {
#pragma unroll
      for (int i = 0; i < 4; ++i) atomicAdd(out + px + i, vsum[i]);
    }
  }
}

// ws path K2: combine the 4 channel-quarter partials, write e, emit
// per-block min/max partials (every slot written -> no init needed).
// Grid 256 x 256 threads, one float4 per thread. Batch = bx>>6.
__global__ __launch_bounds__(256) void combine_minmax(const float* __restrict__ pw,
                                                      float* __restrict__ e,
                                                      float* __restrict__ pm) {
  const int t = blockIdx.x * 256 + threadIdx.x;
  float4 v0 = reinterpret_cast<const float4*>(pw)[t];
  float4 v1 = reinterpret_cast<const float4*>(pw + NPX)[t];
  float4 v2 = reinterpret_cast<const float4*>(pw + 2 * (size_t)NPX)[t];
  float4 v3 = reinterpret_cast<const float4*>(pw + 3 * (size_t)NPX)[t];
  float4 v = make_float4(v0.x + v1.x + v2.x + v3.x, v0.y + v1.y + v2.y + v3.y,
                         v0.z + v1.z + v2.z + v3.z, v0.w + v1.w + v2.w + v3.w);
  reinterpret_cast<float4*>(e)[t] = v;

  float mn = fminf(fminf(v.x, v.y), fminf(v.z, v.w));
  float mx = fmaxf(fmaxf(v.x, v.y), fmaxf(v.z, v.w));
#pragma unroll
  for (int off = 32; off > 0; off >>= 1) {
    mn = fminf(mn, __shfl_down(mn, off, 64));
    mx = fmaxf(mx, __shfl_down(mx, off, 64));
  }
  __shared__ float smn[4], smx[4];
  const int wave = threadIdx.x >> 6;
  if ((threadIdx.x & 63) == 0) { smn[wave] = mn; smx[wave] = mx; }
  __syncthreads();
  if (threadIdx.x == 0) {
    pm[blockIdx.x]       = fminf(fminf(smn[0], smn[1]), fminf(smn[2], smn[3]));
    pm[256 + blockIdx.x] = fmaxf(fmaxf(smx[0], smx[1]), fmaxf(smx[2], smx[3]));
  }
}

// ws path K3: reduce this batch's 64 min/max partials in-wave (redundant per
// wave, cheap), then normalize. Grid 256 x 256, one float4 per thread.
__global__ __launch_bounds__(256) void norm_ws(float* __restrict__ e,
                                               const float* __restrict__ pm) {
  const int b = blockIdx.x >> 6;
  const int lane = threadIdx.x & 63;
  float mn = pm[b * 64 + lane];
  float mx = pm[256 + b * 64 + lane];
#pragma unroll
  for (int off = 32; off > 0; off >>= 1) {
    mn = fminf(mn, __shfl_down(mn, off, 64));
    mx = fmaxf(mx, __shfl_down(mx, off, 64));
  }
  mn = __shfl(mn, 0, 64);
  mx = __shfl(mx, 0, 64);
  const float inv = 1.0f / fmaxf(mx - mn, 1e-6f);

  const int t = blockIdx.x * 256 + threadIdx.x;
  float4 v = reinterpret_cast<float4*>(e)[t];
  v.x = (v.x - mn) * inv;
  v.y = (v.y - mn) * inv;
  v.z = (v.z - mn) * inv;
  v.w = (v.w - mn) * inv;
  reinterpret_cast<float4*>(e)[t] = v;
}

// Fallback path kernels (atomics + memset) — used only if ws is tiny.
__global__ __launch_bounds__(256) void minmax_atomic(const float* __restrict__ e,
                                                     unsigned int* __restrict__ stats) {
  const int bx = blockIdx.x;
  const int b = bx >> 6;
  const float4 v = reinterpret_cast<const float4*>(
      e + (size_t)b * Hh * Ww + (bx & 63) * 1024)[threadIdx.x];
  float mn = fminf(fminf(v.x, v.y), fminf(v.z, v.w));
  float mx = fmaxf(fmaxf(v.x, v.y), fmaxf(v.z, v.w));
#pragma unroll
  for (int off = 32; off > 0; off >>= 1) {
    mn = fminf(mn, __shfl_down(mn, off, 64));
    mx = fmaxf(mx, __shfl_down(mx, off, 64));
  }
  __shared__ float smn[4], smx[4];
  const int wave = threadIdx.x >> 6;
  if ((threadIdx.x & 63) == 0) { smn[wave] = mn; smx[wave] = mx; }
  __syncthreads();
  if (threadIdx.x == 0) {
    atomicMin(&stats[b], fenc(fminf(fminf(smn[0], smn[1]), fminf(smn[2], smn[3]))));
    atomicMax(&stats[4 + b], fenc(fmaxf(fmaxf(smx[0], smx[1]), fmaxf(smx[2], smx[3]))));
  }
}

__global__ __launch_bounds__(256) void norm_atomic(float* __restrict__ e,
                                                   const unsigned int* __restrict__ stats) {
  const int t = blockIdx.x * 256 + threadIdx.x;
  const int b = t >> 14;
  const float mn = fdec(stats[b]);
  const float mx = fdec(stats[4 + b]);
  const float inv = 1.0f / fmaxf(mx - mn, 1e-6f);
  float4 v = reinterpret_cast<float4*>(e)[t];
  v.x = (v.x - mn) * inv;
  v.y = (v.y - mn) * inv;
  v.z = (v.z - mn) * inv;
  v.w = (v.w - mn) * inv;
  reinterpret_cast<float4*>(e)[t] = v;
}

extern "C" void kernel_launch(void* const* d_in, const int* in_sizes, int n_in,
                              void* d_out, int out_size, void* d_ws, size_t ws_size,
                              hipStream_t stream) {
  const float* x = (const float*)d_in[0];
  float* out = (float*)d_out;

  const size_t ws_needed = ((size_t)CS * NPX + 512) * sizeof(float);  // ~4.2 MB
  if (ws_size >= ws_needed) {
    float* pw = (float*)d_ws;                 // [CS][NPX] partials
    float* pm = pw + (size_t)CS * NPX;        // [256 min][256 max]
    entropy_kernel<0><<<dim3(Bb * NSTRIP * CS), dim3(64, 8), 0, stream>>>(x, pw);
    combine_minmax<<<dim3(NPX4 / 256), dim3(256), 0, stream>>>(pw, out, pm);
    norm_ws<<<dim3(NPX4 / 256), dim3(256), 0, stream>>>(out, pm);
  } else {
    unsigned int* stats = (unsigned int*)d_ws;  // 8 uints
    hipMemsetAsync(out, 0, (size_t)NPX * sizeof(float), stream);
    hipMemsetAsync(stats, 0xFF, 4 * sizeof(unsigned int), stream);
    hipMemsetAsync(stats + 4, 0x00, 4 * sizeof(unsigned int), stream);
    entropy_kernel<1><<<dim3(Bb * NSTRIP * CS), dim3(64, 8), 0, stream>>>(x, out);
    minmax_atomic<<<dim3(Bb * 64), dim3(256), 0, stream>>>(out, stats);
    norm_atomic<<<dim3(NPX4 / 256), dim3(256), 0, stream>>>(out, stats);
  }
}